// Round 9
// baseline (149.922 us; speedup 1.0000x reference)
//
#include <hip/hip_runtime.h>
#include <math.h>

// KPConv fused, round 9: R8 numerics bit-identical; latency fixes only.
//  - Phase B gather pipeline CH 8 -> 16 (covers L3 latency)
//  - Phase C: double-buffered 5-jt load groups pinned with sched_barrier(0)
// Shapes: N=50000, M=50000, H=40, K=15, CIN=64, COUT=128.
typedef unsigned short ushort_t;
typedef __attribute__((ext_vector_type(8))) short bf16x8;   // 8 bf16 = 4 VGPRs
typedef __attribute__((ext_vector_type(4))) float f32x4;

constexpr int H    = 40;
constexpr int KKP  = 15;
constexpr int CIN  = 64;
constexpr int COUT = 128;
constexpr int QB   = 8;          // queries per block
constexpr int NP   = QB * H;     // 320 (q,h) pairs per block
constexpr int SWF  = 984;        // WF16 row stride: 1968 B (16B-aligned, step 3 mod 8)
constexpr float INV_KPE = 1.0f / 1.2f;

__device__ __forceinline__ ushort_t f2bf(float f) {   // fp32 -> bf16 RNE
    union { float f; unsigned u; } v; v.f = f;
    unsigned r = v.u + 0x7FFFu + ((v.u >> 16) & 1u);
    return (ushort_t)(r >> 16);
}
__device__ __forceinline__ float bf2f(ushort_t u) {
    return __uint_as_float(((unsigned)u) << 16);
}

// ---- kernel 1: per-support-row feature sums (reduction order UNCHANGED) + bf16 x copy
__global__ __launch_bounds__(256) void prep_kernel(const float* __restrict__ x,
                                                   float* __restrict__ rowsum,
                                                   ushort_t* __restrict__ xb,
                                                   int M, int write_xb) {
    int row  = blockIdx.x * 4 + (threadIdx.x >> 6);
    int lane = threadIdx.x & 63;
    if (row >= M) return;
    float v = x[row * CIN + lane];   // CIN == 64 == wave width
    if (write_xb) xb[row * CIN + lane] = f2bf(v);
    #pragma unroll
    for (int off = 32; off > 0; off >>= 1) v += __shfl_down(v, off, 64);
    if (lane == 0) rowsum[row] = v;
}

// ---- kernel 2: W -> bf16 MFMA-fragment order (UNCHANGED, validated R2/R3/R5/R8)
__global__ __launch_bounds__(256) void wprep_kernel(const float* __restrict__ wmat,
                                                    ushort_t* __restrict__ wb) {
    int t = blockIdx.x * 256 + threadIdx.x;
    if (t >= 30 * 8 * 64) return;
    int lane = t & 63;
    int ot   = (t >> 6) & 7;
    int jt   = t >> 9;
    int o  = ot * 16 + (lane & 15);
    int kb = jt * 32 + (lane >> 4) * 8;
    unsigned pk[4];
    #pragma unroll
    for (int r = 0; r < 4; ++r) {
        unsigned lo = f2bf(wmat[(kb + 2 * r) * COUT + o]);
        unsigned hi = f2bf(wmat[(kb + 2 * r + 1) * COUT + o]);
        pk[r] = lo | (hi << 16);
    }
    *(uint4*)&wb[(size_t)t * 8] = make_uint4(pk[0], pk[1], pk[2], pk[3]);
}

// ---- kernel 3: fused KPConv ---------------------------------------------------
// LDS: w_p 20480 + cind 1280 + qcnt 32 + cnt 32 + WF16 15744 = 37568 B -> 4 blk/CU
template<bool BF16X>
__global__ __launch_bounds__(256, 4) void kpconv_main(
    const float* __restrict__ q_pts, const float* __restrict__ s_pts,
    const int*   __restrict__ nbinds, const float* __restrict__ xf,
    const ushort_t* __restrict__ xb,  const float* __restrict__ kp,
    const ushort_t* __restrict__ wb,  const float* __restrict__ rowsum,
    float* __restrict__ out, int N, int M)
{
    __shared__ __align__(16) float w_p[NP * 16];      // [slot-row][16] f32 (15 + pad)
    __shared__ int      cind[NP];                     // [q][slot] -> support row index
    __shared__ int      qcnt[QB];                     // active slots per q
    __shared__ int      cnt[QB];                      // valid-neighbor count (normalizer)
    __shared__ __align__(16) ushort_t WF16[QB * SWF]; // bf16 WF, [q][j], padded stride

    const int tid = threadIdx.x;
    const int q0  = blockIdx.x * QB;

    if (tid < QB) { qcnt[tid] = 0; cnt[tid] = 0; }
    __syncthreads();

    // ---------------- Phase A: KP weights + validity + compaction --------------
    // (byte-identical math to R5/R8)
    for (int p = tid; p < NP; p += 256) {
        int q  = p / H;
        int h  = p - q * H;
        int gq = q0 + q;
        int ind = nbinds[gq * H + h];
        bool shadow = (ind >= M);
        float nx = 0.f, ny = 0.f, nz = 0.f;
        if (!shadow) {
            nx = s_pts[ind * 3 + 0] - q_pts[gq * 3 + 0];
            ny = s_pts[ind * 3 + 1] - q_pts[gq * 3 + 1];
            nz = s_pts[ind * 3 + 2] - q_pts[gq * 3 + 2];
            if (rowsum[ind] > 0.0f) atomicAdd(&cnt[q], 1);
        }
        float n2 = nx * nx + ny * ny + nz * nz;
        float w[16];
        float wmax = 0.f;
        #pragma unroll
        for (int k = 0; k < KKP; ++k) {
            float wv = 0.f;
            if (!shadow) {
                float kx = kp[k * 3 + 0], ky = kp[k * 3 + 1], kz = kp[k * 3 + 2];
                float k2 = kx * kx + ky * ky + kz * kz;
                float cross = nx * kx + ny * ky + nz * kz;
                float sq = fmaxf(n2 + k2 - 2.0f * cross, 0.0f);
                wv = fmaxf(1.0f - sqrtf(sq) * INV_KPE, 0.0f);
            }
            w[k] = wv;
            wmax = fmaxf(wmax, wv);
        }
        w[15] = 0.f;
        if (wmax > 0.f) {
            int slot = atomicAdd(&qcnt[q], 1);
            int row  = q * H + slot;          // slot-compacted w row
            cind[row] = ind;
            f32x4* dst = (f32x4*)&w_p[row * 16];
            dst[0] = (f32x4){w[0],  w[1],  w[2],  w[3]};
            dst[1] = (f32x4){w[4],  w[5],  w[6],  w[7]};
            dst[2] = (f32x4){w[8],  w[9],  w[10], w[11]};
            dst[3] = (f32x4){w[12], w[13], w[14], w[15]};
        }
    }
    __syncthreads();

    // ---------------- Phase B: WF[q][k*64+c], 16-deep pipelined gather ---------
    const int wid = tid >> 6;   // wave id 0..3
    const int c   = tid & 63;
    constexpr int CH = 16;      // gather pipeline depth (covers L3 latency)
    for (int r = 0; r < 2; ++r) {
        int q  = r * 4 + wid;
        int nc = qcnt[q];       // wave-uniform
        int qH = q * H;
        float acc[KKP];
        #pragma unroll
        for (int k = 0; k < KKP; ++k) acc[k] = 0.f;

        if (nc > 0) {
            float xcur[CH], xnxt[CH];
            #pragma unroll
            for (int j = 0; j < CH; ++j) {   // prologue: chunk 0 loads
                int ind = cind[qH + min(j, nc - 1)];
                xcur[j] = BF16X ? bf2f(xb[(size_t)ind * CIN + c])
                                : xf[(size_t)ind * CIN + c];
            }
            for (int base = 0; base < nc; base += CH) {
                #pragma unroll
                for (int j = 0; j < CH; ++j) {   // prefetch next chunk (clamped)
                    int ind = cind[qH + min(base + CH + j, nc - 1)];
                    xnxt[j] = BF16X ? bf2f(xb[(size_t)ind * CIN + c])
                                    : xf[(size_t)ind * CIN + c];
                }
                #pragma unroll
                for (int j = 0; j < CH; ++j) {
                    if (base + j < nc) {         // wave-uniform predicate
                        const f32x4* wr = (const f32x4*)&w_p[(qH + base + j) * 16];
                        f32x4 w0 = wr[0], w1 = wr[1], w2 = wr[2], w3 = wr[3];
                        float xv = xcur[j];
                        acc[0]  += w0[0] * xv; acc[1]  += w0[1] * xv;
                        acc[2]  += w0[2] * xv; acc[3]  += w0[3] * xv;
                        acc[4]  += w1[0] * xv; acc[5]  += w1[1] * xv;
                        acc[6]  += w1[2] * xv; acc[7]  += w1[3] * xv;
                        acc[8]  += w2[0] * xv; acc[9]  += w2[1] * xv;
                        acc[10] += w2[2] * xv; acc[11] += w2[3] * xv;
                        acc[12] += w3[0] * xv; acc[13] += w3[1] * xv;
                        acc[14] += w3[2] * xv;
                    }
                }
                #pragma unroll
                for (int j = 0; j < CH; ++j) xcur[j] = xnxt[j];
            }
        }
        #pragma unroll
        for (int k = 0; k < KKP; ++k)
            WF16[q * SWF + k * 64 + c] = f2bf(acc[k]);     // stride-1 b16 writes
    }
    __syncthreads();

    // ---------------- Phase C: MFMA with double-buffered 5-jt load groups ------
    {
        const int lane = tid & 63;
        const int qrow = lane & 7;
        const int kg   = lane >> 4;
        const int ot0  = wid * 2;
        f32x4 c0 = {0.f,0.f,0.f,0.f}, c1 = {0.f,0.f,0.f,0.f};
        const ushort_t* wfrow = &WF16[qrow * SWF + kg * 8];
        const ushort_t* bbase = wb + ((size_t)(ot0 * 64 + lane)) * 8;

        constexpr int GC = 5;            // jt per group; 6 groups of 5 = 30
        bf16x8 ga0[GC], ga1[GC], gb0[GC], gb1[GC];
        #pragma unroll
        for (int u = 0; u < GC; ++u) {   // group 0 -> set A
            ga0[u] = *(const bf16x8*)&bbase[(size_t)u * 4096];
            ga1[u] = *(const bf16x8*)&bbase[(size_t)u * 4096 + 512];
        }
        #pragma unroll
        for (int g = 0; g < 6; ++g) {
            const int jb = g * GC;
            if ((g & 1) == 0) {
                if (g < 5) {             // prefetch group g+1 -> set B
                    #pragma unroll
                    for (int u = 0; u < GC; ++u) {
                        gb0[u] = *(const bf16x8*)&bbase[(size_t)(jb + GC + u) * 4096];
                        gb1[u] = *(const bf16x8*)&bbase[(size_t)(jb + GC + u) * 4096 + 512];
                    }
                }
                __builtin_amdgcn_sched_barrier(0);   // pin: loads issued before MFMAs
                #pragma unroll
                for (int u = 0; u < GC; ++u) {
                    bf16x8 a = *(const bf16x8*)&wfrow[(jb + u) * 32];
                    c0 = __builtin_amdgcn_mfma_f32_16x16x32_bf16(a, ga0[u], c0, 0, 0, 0);
                    c1 = __builtin_amdgcn_mfma_f32_16x16x32_bf16(a, ga1[u], c1, 0, 0, 0);
                }
            } else {
                if (g < 5) {             // prefetch group g+1 -> set A
                    #pragma unroll
                    for (int u = 0; u < GC; ++u) {
                        ga0[u] = *(const bf16x8*)&bbase[(size_t)(jb + GC + u) * 4096];
                        ga1[u] = *(const bf16x8*)&bbase[(size_t)(jb + GC + u) * 4096 + 512];
                    }
                }
                __builtin_amdgcn_sched_barrier(0);
                #pragma unroll
                for (int u = 0; u < GC; ++u) {
                    bf16x8 a = *(const bf16x8*)&wfrow[(jb + u) * 32];
                    c0 = __builtin_amdgcn_mfma_f32_16x16x32_bf16(a, gb0[u], c0, 0, 0, 0);
                    c1 = __builtin_amdgcn_mfma_f32_16x16x32_bf16(a, gb1[u], c1, 0, 0, 0);
                }
            }
        }

        // C/D layout: col = lane&15, row = (lane>>4)*4 + reg. Rows 0..7 = queries.
        if (lane < 32) {
            int col = ot0 * 16 + (lane & 15);
            #pragma unroll
            for (int reg = 0; reg < 4; ++reg) {
                int row = (lane >> 4) * 4 + reg;
                float inv = 1.0f / (float)max(cnt[row], 1);
                int gq = q0 + row;
                if (gq < N) {
                    out[(size_t)gq * COUT + col]      = c0[reg] * inv;
                    out[(size_t)gq * COUT + col + 16] = c1[reg] * inv;
                }
            }
        }
    }
}

extern "C" void kernel_launch(void* const* d_in, const int* in_sizes, int n_in,
                              void* d_out, int out_size, void* d_ws, size_t ws_size,
                              hipStream_t stream) {
    const float* q_pts  = (const float*)d_in[0];
    const float* s_pts  = (const float*)d_in[1];
    const int*   nbinds = (const int*)d_in[2];
    const float* x      = (const float*)d_in[3];
    const float* kp     = (const float*)d_in[4];
    const float* wmat   = (const float*)d_in[5];
    float* out = (float*)d_out;
    int N = in_sizes[0] / 3;
    int M = in_sizes[1] / 3;

    // workspace carve: rowsum (M f32) | wb (245760 B) | xb (M*64 bf16)
    size_t    off_wb = ((size_t)M * 4 + 255) & ~(size_t)255;
    size_t    off_xb = (off_wb + 245760 + 255) & ~(size_t)255;
    size_t    need   = off_xb + (size_t)M * CIN * 2;
    float*    rowsum = (float*)d_ws;
    ushort_t* wb     = (ushort_t*)((char*)d_ws + off_wb);
    ushort_t* xb     = (ushort_t*)((char*)d_ws + off_xb);
    bool use_bf16x = (ws_size >= need);

    prep_kernel<<<(M + 3) / 4, 256, 0, stream>>>(x, rowsum, xb, M, use_bf16x ? 1 : 0);
    wprep_kernel<<<60, 256, 0, stream>>>(wmat, wb);
    int mb = (N + QB - 1) / QB;
    if (use_bf16x)
        kpconv_main<true><<<mb, 256, 0, stream>>>(q_pts, s_pts, nbinds, x, xb, kp,
                                                  wb, rowsum, out, N, M);
    else
        kpconv_main<false><<<mb, 256, 0, stream>>>(q_pts, s_pts, nbinds, x, xb, kp,
                                                   wb, rowsum, out, N, M);
}

// Round 10
// 123.917 us; speedup vs baseline: 1.2099x; 1.2099x over previous
//
#include <hip/hip_runtime.h>
#include <math.h>

// KPConv fused, round 10: Phase B moved onto MFMA.
//   A = w^T staged in LDS (validated A-frag layout, ds_read_b128)
//   B = x gathered straight into registers (validated B-frag k-order)
//   Phase A math, Phase C, prep/wprep: byte-identical to R8 (passed, 140us).
// Shapes: N=50000, M=50000, H=40, K=15, CIN=64, COUT=128.
typedef unsigned short ushort_t;
typedef __attribute__((ext_vector_type(8))) short bf16x8;   // 8 bf16 = 4 VGPRs
typedef __attribute__((ext_vector_type(4))) float f32x4;

constexpr int H    = 40;
constexpr int KKP  = 15;
constexpr int CIN  = 64;
constexpr int COUT = 128;
constexpr int QB   = 8;          // queries per block
constexpr int NP   = QB * H;     // 320 (q,h) pairs per block
constexpr int SWF  = 984;        // WF16 row stride (validated in R8 Phase C)
constexpr int SWT  = 536;        // wT row stride elems: 1072B = 16B-mult; 2-way banks
constexpr float INV_KPE = 1.0f / 1.2f;

__device__ __forceinline__ ushort_t f2bf(float f) {   // fp32 -> bf16 RNE
    union { float f; unsigned u; } v; v.f = f;
    unsigned r = v.u + 0x7FFFu + ((v.u >> 16) & 1u);
    return (ushort_t)(r >> 16);
}
__device__ __forceinline__ unsigned pk2(ushort_t a, ushort_t b) {
    return (unsigned)a | ((unsigned)b << 16);
}

// ---- kernel 1: per-support-row feature sums (reduction order UNCHANGED) + bf16 x copy
__global__ __launch_bounds__(256) void prep_kernel(const float* __restrict__ x,
                                                   float* __restrict__ rowsum,
                                                   ushort_t* __restrict__ xb,
                                                   int M, int write_xb) {
    int row  = blockIdx.x * 4 + (threadIdx.x >> 6);
    int lane = threadIdx.x & 63;
    if (row >= M) return;
    float v = x[row * CIN + lane];   // CIN == 64 == wave width
    if (write_xb) xb[row * CIN + lane] = f2bf(v);
    #pragma unroll
    for (int off = 32; off > 0; off >>= 1) v += __shfl_down(v, off, 64);
    if (lane == 0) rowsum[row] = v;
}

// ---- kernel 2: W -> bf16 MFMA-fragment order (UNCHANGED, validated R2..R8) ----
__global__ __launch_bounds__(256) void wprep_kernel(const float* __restrict__ wmat,
                                                    ushort_t* __restrict__ wb) {
    int t = blockIdx.x * 256 + threadIdx.x;
    if (t >= 30 * 8 * 64) return;
    int lane = t & 63;
    int ot   = (t >> 6) & 7;
    int jt   = t >> 9;
    int o  = ot * 16 + (lane & 15);
    int kb = jt * 32 + (lane >> 4) * 8;
    unsigned pk[4];
    #pragma unroll
    for (int r = 0; r < 4; ++r) {
        unsigned lo = f2bf(wmat[(kb + 2 * r) * COUT + o]);
        unsigned hi = f2bf(wmat[(kb + 2 * r + 1) * COUT + o]);
        pk[r] = lo | (hi << 16);
    }
    *(uint4*)&wb[(size_t)t * 8] = make_uint4(pk[0], pk[1], pk[2], pk[3]);
}

// ---- kernel 3: fused KPConv ---------------------------------------------------
// LDS: wT 17152 + WF16 15744 + cind 2048 + qcnt 32 + cnt 32 = 35008 B -> 4 blk/CU
template<bool BF16X>
__global__ __launch_bounds__(256, 4) void kpconv_main(
    const float* __restrict__ q_pts, const float* __restrict__ s_pts,
    const int*   __restrict__ nbinds, const float* __restrict__ xf,
    const ushort_t* __restrict__ xb,  const float* __restrict__ kp,
    const ushort_t* __restrict__ wb,  const float* __restrict__ rowsum,
    float* __restrict__ out, int N, int M)
{
    __shared__ __align__(16) ushort_t wT[16 * SWT];   // w^T: [kp][q*64+slot] bf16
    __shared__ __align__(16) ushort_t WF16[QB * SWF]; // bf16 WF, [q][k*64+c]
    __shared__ int cind[QB * 64];                     // [q][slot] -> support row (0-init)
    __shared__ int qcnt[QB];                          // active slots per q
    __shared__ int cnt[QB];                           // valid-neighbor count (normalizer)

    const int tid = threadIdx.x;
    const int q0  = blockIdx.x * QB;

    // zero wT (pad slots/kp15 must be 0) and cind (pad slots -> row 0, finite x)
    for (int i = tid; i < 16 * SWT / 8; i += 256)
        ((uint4*)wT)[i] = make_uint4(0, 0, 0, 0);
    for (int i = tid; i < QB * 64; i += 256) cind[i] = 0;
    if (tid < QB) { qcnt[tid] = 0; cnt[tid] = 0; }
    __syncthreads();

    // ---------------- Phase A: KP weights + validity + compaction --------------
    // (math byte-identical to R8; only the w store target changed: wT bf16)
    for (int p = tid; p < NP; p += 256) {
        int q  = p / H;
        int h  = p - q * H;
        int gq = q0 + q;
        int ind = nbinds[gq * H + h];
        bool shadow = (ind >= M);
        float nx = 0.f, ny = 0.f, nz = 0.f;
        if (!shadow) {
            nx = s_pts[ind * 3 + 0] - q_pts[gq * 3 + 0];
            ny = s_pts[ind * 3 + 1] - q_pts[gq * 3 + 1];
            nz = s_pts[ind * 3 + 2] - q_pts[gq * 3 + 2];
            if (rowsum[ind] > 0.0f) atomicAdd(&cnt[q], 1);
        }
        float n2 = nx * nx + ny * ny + nz * nz;
        float w[KKP];
        float wmax = 0.f;
        #pragma unroll
        for (int k = 0; k < KKP; ++k) {
            float wv = 0.f;
            if (!shadow) {
                float kx = kp[k * 3 + 0], ky = kp[k * 3 + 1], kz = kp[k * 3 + 2];
                float k2 = kx * kx + ky * ky + kz * kz;
                float cross = nx * kx + ny * ky + nz * kz;
                float sq = fmaxf(n2 + k2 - 2.0f * cross, 0.0f);
                wv = fmaxf(1.0f - sqrtf(sq) * INV_KPE, 0.0f);
            }
            w[k] = wv;
            wmax = fmaxf(wmax, wv);
        }
        if (wmax > 0.f) {
            int slot = atomicAdd(&qcnt[q], 1);
            int col  = q * 64 + slot;
            cind[col] = ind;
            #pragma unroll
            for (int k = 0; k < KKP; ++k)
                wT[k * SWT + col] = f2bf(w[k]);   // transposed store
        }
    }
    __syncthreads();

    // ---------------- Phase B: WF[q] via MFMA ----------------------------------
    // A-frag: lane holds wT[kp=lane&15][q*64 + kg*8 + i]   (ds_read_b128)
    // B-frag: lane holds x[slot=kg*8+i][chan=wid*16+l15]   (register gather)
    // D:      row=(lane>>4)*4+reg -> kp, col=lane&15 -> chan (validated layout)
    const int wid  = tid >> 6;
    const int lane = tid & 63;
    const int l15  = lane & 15;
    const int kg   = lane >> 4;
    const int chan = wid * 16 + l15;

    ushort_t va[16], vbuf[16];
    // LOADQ: gather the 16 B-frag values for query qq into arr
    #define LOADQ(qq, arr)                                                        \
        {                                                                         \
            const int cb_ = (qq) * 64;                                            \
            _Pragma("unroll")                                                     \
            for (int i = 0; i < 8; ++i) {                                         \
                int i0 = cind[cb_ + kg * 8 + i];                                  \
                int i1 = cind[cb_ + 32 + kg * 8 + i];                             \
                if (BF16X) {                                                      \
                    (arr)[i]     = xb[((unsigned)i0 << 6) + chan];                \
                    (arr)[8 + i] = xb[((unsigned)i1 << 6) + chan];                \
                } else {                                                          \
                    (arr)[i]     = f2bf(xf[((unsigned)i0 << 6) + chan]);          \
                    (arr)[8 + i] = f2bf(xf[((unsigned)i1 << 6) + chan]);          \
                }                                                                 \
            }                                                                     \
        }
    #define CONSUMEQ(qq, arr)                                                     \
        {                                                                         \
            union { uint4 u; bf16x8 b; } b0_, b1_;                                \
            b0_.u = make_uint4(pk2((arr)[0], (arr)[1]),  pk2((arr)[2], (arr)[3]), \
                               pk2((arr)[4], (arr)[5]),  pk2((arr)[6], (arr)[7]));\
            b1_.u = make_uint4(pk2((arr)[8], (arr)[9]),  pk2((arr)[10],(arr)[11]),\
                               pk2((arr)[12],(arr)[13]), pk2((arr)[14],(arr)[15]));\
            bf16x8 a0_ = *(const bf16x8*)&wT[l15 * SWT + (qq) * 64 + kg * 8];     \
            bf16x8 a1_ = *(const bf16x8*)&wT[l15 * SWT + (qq) * 64 + 32 + kg * 8];\
            f32x4 acc_ = {0.f, 0.f, 0.f, 0.f};                                    \
            acc_ = __builtin_amdgcn_mfma_f32_16x16x32_bf16(a0_, b0_.b, acc_, 0,0,0);\
            acc_ = __builtin_amdgcn_mfma_f32_16x16x32_bf16(a1_, b1_.b, acc_, 0,0,0);\
            _Pragma("unroll")                                                     \
            for (int reg = 0; reg < 4; ++reg) {                                   \
                int kpr = kg * 4 + reg;                                           \
                if (kpr < KKP)                                                    \
                    WF16[(qq) * SWF + kpr * 64 + chan] = f2bf(acc_[reg]);         \
            }                                                                     \
        }

    LOADQ(0, va);
    #pragma unroll
    for (int q = 0; q < QB; q += 2) {
        if (q + 1 < QB) LOADQ(q + 1, vbuf);
        CONSUMEQ(q, va);
        if (q + 2 < QB) LOADQ(q + 2, va);
        if (q + 1 < QB) CONSUMEQ(q + 1, vbuf);
    }
    #undef LOADQ
    #undef CONSUMEQ
    __syncthreads();

    // ---------------- Phase C: out[q][o] via MFMA, 6-deep wb prefetch (R8) -----
    {
        const int qrow = lane & 7;
        const int ot0  = wid * 2;
        f32x4 c0 = {0.f,0.f,0.f,0.f}, c1 = {0.f,0.f,0.f,0.f};
        const ushort_t* wfrow = &WF16[qrow * SWF + kg * 8];
        const ushort_t* bbase = wb + ((size_t)(ot0 * 64 + lane)) * 8;

        bf16x8 rb0[6], rb1[6];
        #pragma unroll
        for (int i = 0; i < 6; ++i) {        // preload jt = 0..5
            rb0[i] = *(const bf16x8*)&bbase[(size_t)i * 4096];
            rb1[i] = *(const bf16x8*)&bbase[(size_t)i * 4096 + 512];
        }
        for (int m = 0; m < 5; ++m) {        // 5 x 6 = 30 jt steps
            #pragma unroll
            for (int u = 0; u < 6; ++u) {
                int jt = m * 6 + u;
                bf16x8 a = *(const bf16x8*)&wfrow[jt * 32];
                c0 = __builtin_amdgcn_mfma_f32_16x16x32_bf16(a, rb0[u], c0, 0, 0, 0);
                c1 = __builtin_amdgcn_mfma_f32_16x16x32_bf16(a, rb1[u], c1, 0, 0, 0);
                if (m < 4) {                 // prefetch jt+6 into freed slot
                    rb0[u] = *(const bf16x8*)&bbase[(size_t)(jt + 6) * 4096];
                    rb1[u] = *(const bf16x8*)&bbase[(size_t)(jt + 6) * 4096 + 512];
                }
            }
        }

        // C/D layout: col = lane&15, row = (lane>>4)*4 + reg. Rows 0..7 = queries.
        if (lane < 32) {
            int col = ot0 * 16 + (lane & 15);
            #pragma unroll
            for (int reg = 0; reg < 4; ++reg) {
                int row = (lane >> 4) * 4 + reg;
                float inv = 1.0f / (float)max(cnt[row], 1);
                int gq = q0 + row;
                if (gq < N) {
                    out[(size_t)gq * COUT + col]      = c0[reg] * inv;
                    out[(size_t)gq * COUT + col + 16] = c1[reg] * inv;
                }
            }
        }
    }
}

extern "C" void kernel_launch(void* const* d_in, const int* in_sizes, int n_in,
                              void* d_out, int out_size, void* d_ws, size_t ws_size,
                              hipStream_t stream) {
    const float* q_pts  = (const float*)d_in[0];
    const float* s_pts  = (const float*)d_in[1];
    const int*   nbinds = (const int*)d_in[2];
    const float* x      = (const float*)d_in[3];
    const float* kp     = (const float*)d_in[4];
    const float* wmat   = (const float*)d_in[5];
    float* out = (float*)d_out;
    int N = in_sizes[0] / 3;
    int M = in_sizes[1] / 3;

    // workspace carve: rowsum (M f32) | wb (245760 B) | xb (M*64 bf16)
    size_t    off_wb = ((size_t)M * 4 + 255) & ~(size_t)255;
    size_t    off_xb = (off_wb + 245760 + 255) & ~(size_t)255;
    size_t    need   = off_xb + (size_t)M * CIN * 2;
    float*    rowsum = (float*)d_ws;
    ushort_t* wb     = (ushort_t*)((char*)d_ws + off_wb);
    ushort_t* xb     = (ushort_t*)((char*)d_ws + off_xb);
    bool use_bf16x = (ws_size >= need);

    prep_kernel<<<(M + 3) / 4, 256, 0, stream>>>(x, rowsum, xb, M, use_bf16x ? 1 : 0);
    wprep_kernel<<<60, 256, 0, stream>>>(wmat, wb);
    int mb = (N + QB - 1) / QB;
    if (use_bf16x)
        kpconv_main<true><<<mb, 256, 0, stream>>>(q_pts, s_pts, nbinds, x, xb, kp,
                                                  wb, rowsum, out, N, M);
    else
        kpconv_main<false><<<mb, 256, 0, stream>>>(q_pts, s_pts, nbinds, x, xb, kp,
                                                   wb, rowsum, out, N, M);
}